// Round 9
// baseline (890.206 us; speedup 1.0000x reference)
//
#include <hip/hip_runtime.h>
#include <math.h>

#define BB 64
#define CC 768
#define NN 1024
#define BS 192
#define EPS 1e-5f
#define LAM 0.01f

typedef float  f32x4  __attribute__((ext_vector_type(4)));
typedef short  bf16x8 __attribute__((ext_vector_type(8)));

__device__ inline unsigned f2bf(float x) {
    unsigned u = __float_as_uint(x);
    u += 0x7fff + ((u >> 16) & 1);   // RNE
    return u >> 16;
}
__device__ inline unsigned pack2(float r, float i) { return f2bf(r) | (f2bf(i) << 16); }
__device__ inline float bflo(unsigned v) { return __uint_as_float(v << 16); }
__device__ inline float bfhi(unsigned v) { return __uint_as_float(v & 0xffff0000u); }

// LDS bank swizzle on float2 index (FFT kernels only): XOR bits 4-5 into 2-3.
__device__ inline int swz(int i) { return i ^ (((i >> 4) & 3) << 2); }

// H-panel LDS index: row-major [192][64] dwords, XOR swizzle (2 lanes/bank on
// both the epilogue-1 write pattern and the layer-2 fragment read pattern,
// including the m-half split: bank = (col ^ sw) mod 32, col-halves shift by
// 32 ≡ 0 (mod 32) so the per-instruction analysis is unchanged).
__device__ inline int hidx(int row, int col) {
    return row * 64 + (col ^ (((row >> 1) & 3) << 3));
}

// ---------------------------------------------------------------------------
// Kernel 1: LayerNorm statistics per (b, n). float4-vectorized along n.
// ---------------------------------------------------------------------------
__global__ __launch_bounds__(512) void ln_stats(const float* __restrict__ x,
                                                float* __restrict__ mu,
                                                float* __restrict__ rstd) {
    int tn = threadIdx.x & 63, tc = threadIdx.x >> 6;   // tc: 0..7
    int n = blockIdx.x * 256 + tn * 4, b = blockIdx.y;
    const float* xp = x + (size_t)b * CC * NN + n;
    f32x4 s = (f32x4)0.f, ss = (f32x4)0.f;
    #pragma unroll 4
    for (int c = tc; c < CC; c += 8) {
        f32x4 v = *(const f32x4*)(xp + (size_t)c * NN);
        s += v; ss += v * v;
    }
    __shared__ f32x4 sm[8][64], sq[8][64];
    sm[tc][tn] = s; sq[tc][tn] = ss;
    __syncthreads();
    if (tc == 0) {
        f32x4 S  = sm[0][tn], SS = sq[0][tn];
        #pragma unroll
        for (int i = 1; i < 8; i++) { S += sm[i][tn]; SS += sq[i][tn]; }
        f32x4 m = S * (1.f / 768.f);
        f32x4 r;
        #pragma unroll
        for (int i = 0; i < 4; i++) {
            float var = SS[i] * (1.f / 768.f) - m[i] * m[i];
            r[i] = rsqrtf(var + EPS);
        }
        *(f32x4*)(mu + (size_t)b * NN + n)   = m;
        *(f32x4*)(rstd + (size_t)b * NN + n) = r;
    }
}

// ---------------------------------------------------------------------------
// Kernel 2: LN-apply + 1024-pt radix-4 DIF FFT (n) + 4-pt DFT (q) + 1/64.
// First stage (L=256) folded into the LN-load.
// ---------------------------------------------------------------------------
__global__ void fwd_fft(const float* __restrict__ x,
                        const float* __restrict__ mu_, const float* __restrict__ rs_,
                        const float* __restrict__ gamma, const float* __restrict__ beta,
                        unsigned* __restrict__ Xp) {
    __shared__ float2 bufs[4][1024];
    int d = blockIdx.x, b = blockIdx.y, tid = threadIdx.x;

    float s1f, c1f;
    __sincosf(-(float)M_PI * 0.5f * (float)tid / 256.f, &s1f, &c1f);
    float c2f = c1f * c1f - s1f * s1f, s2f = 2.f * c1f * s1f;
    float c3f = c2f * c1f - s2f * s1f, s3f = c2f * s1f + s2f * c1f;

    const float* mp = mu_ + b * NN;
    const float* rp = rs_ + b * NN;
    #pragma unroll
    for (int q = 0; q < 4; q++) {
        int c = q * BS + d;
        float g = gamma[c], be = beta[c];
        const float* xp = x + ((size_t)b * CC + c) * NN;
        float v0 = (xp[tid]       - mp[tid])       * rp[tid]       * g + be;
        float v1 = (xp[tid + 256] - mp[tid + 256]) * rp[tid + 256] * g + be;
        float v2 = (xp[tid + 512] - mp[tid + 512]) * rp[tid + 512] * g + be;
        float v3 = (xp[tid + 768] - mp[tid + 768]) * rp[tid + 768] * g + be;
        float t0 = v0 + v2, t1 = v0 - v2, t2 = v1 + v3, t3 = v1 - v3;
        bufs[q][swz(tid)]       = make_float2(t0 + t2, 0.f);
        bufs[q][swz(tid + 256)] = make_float2(t1 * c1f + t3 * s1f, t1 * s1f - t3 * c1f);
        bufs[q][swz(tid + 512)] = make_float2((t0 - t2) * c2f, (t0 - t2) * s2f);
        bufs[q][swz(tid + 768)] = make_float2(t1 * c3f - t3 * s3f, t1 * s3f + t3 * c3f);
    }
    __syncthreads();

    #pragma unroll
    for (int sL = 0; sL < 3; sL++) {
        const int L = 64 >> (2 * sL);
        int j = tid & (L - 1);
        int base = ((tid - j) << 2) + j;
        float s1, c1;
        __sincosf(-(float)M_PI * 0.5f * (float)j / (float)L, &s1, &c1);
        float c2 = c1 * c1 - s1 * s1, s2 = 2.f * c1 * s1;
        float c3 = c2 * c1 - s2 * s1, s3 = c2 * s1 + s2 * c1;
        #pragma unroll
        for (int q = 0; q < 4; q++) {
            float2 a  = bufs[q][swz(base)];
            float2 bb = bufs[q][swz(base + L)];
            float2 cc = bufs[q][swz(base + 2 * L)];
            float2 dd = bufs[q][swz(base + 3 * L)];
            float t0r = a.x + cc.x, t0i = a.y + cc.y;
            float t1r = a.x - cc.x, t1i = a.y - cc.y;
            float t2r = bb.x + dd.x, t2i = bb.y + dd.y;
            float t3r = bb.x - dd.x, t3i = bb.y - dd.y;
            float X0r = t0r + t2r, X0i = t0i + t2i;
            float X2r = t0r - t2r, X2i = t0i - t2i;
            float X1r = t1r + t3i, X1i = t1i - t3r;
            float X3r = t1r - t3i, X3i = t1i + t3r;
            bufs[q][swz(base)]         = make_float2(X0r, X0i);
            bufs[q][swz(base + L)]     = make_float2(X1r * c1 - X1i * s1, X1r * s1 + X1i * c1);
            bufs[q][swz(base + 2 * L)] = make_float2(X2r * c2 - X2i * s2, X2r * s2 + X2i * c2);
            bufs[q][swz(base + 3 * L)] = make_float2(X3r * c3 - X3i * s3, X3r * s3 + X3i * c3);
        }
        __syncthreads();
    }

    float Xr[4][4], Xi[4][4];
    int i0 = swz(4 * tid);
    #pragma unroll
    for (int q = 0; q < 4; q++) {
        const float4* p = (const float4*)&bufs[q][i0];
        float4 u0 = p[0], u1 = p[1];
        float t0r = u0.x + u1.x, t0i = u0.y + u1.y;
        float t1r = u0.x - u1.x, t1i = u0.y - u1.y;
        float t2r = u0.z + u1.z, t2i = u0.w + u1.w;
        float t3r = u0.z - u1.z, t3i = u0.w - u1.w;
        Xr[q][0] = t0r + t2r; Xi[q][0] = t0i + t2i;
        Xr[q][1] = t1r + t3i; Xi[q][1] = t1i - t3r;
        Xr[q][2] = t0r - t2r; Xi[q][2] = t0i - t2i;
        Xr[q][3] = t1r - t3i; Xi[q][3] = t1i + t3r;
    }
    const float sc = 1.f / 64.f;
    unsigned o0[4], o1[4], o2[4], o3[4];
    #pragma unroll
    for (int m = 0; m < 4; m++) {
        float x0r = Xr[0][m], x0i = Xi[0][m];
        float x1r = Xr[1][m], x1i = Xi[1][m];
        float x2r = Xr[2][m], x2i = Xi[2][m];
        float x3r = Xr[3][m], x3i = Xi[3][m];
        float X0r = x0r + x1r + x2r + x3r, X0i = x0i + x1i + x2i + x3i;
        float X2r = x0r - x1r + x2r - x3r, X2i = x0i - x1i + x2i - x3i;
        float X1r = x0r + x1i - x2r - x3i, X1i = x0i - x1r - x2i + x3r;
        float X3r = x0r - x1i - x2r + x3i, X3i = x0i + x1r - x2i - x3r;
        o0[m] = pack2(X0r * sc, X0i * sc);
        o1[m] = pack2(X1r * sc, X1i * sc);
        o2[m] = pack2(X2r * sc, X2i * sc);
        o3[m] = pack2(X3r * sc, X3i * sc);
    }
    size_t qs = (size_t)BS * NN;
    size_t base = (((size_t)b * 4) * BS + d) * NN + 4 * tid;
    *(uint4*)(Xp + base)          = make_uint4(o0[0], o0[1], o0[2], o0[3]);
    *(uint4*)(Xp + base + qs)     = make_uint4(o1[0], o1[1], o1[2], o1[3]);
    *(uint4*)(Xp + base + 2 * qs) = make_uint4(o2[0], o2[1], o2[2], o2[3]);
    *(uint4*)(Xp + base + 3 * qs) = make_uint4(o3[0], o3[1], o3[2], o3[3]);
}

// ---------------------------------------------------------------------------
// Kernel 2b: one-time B prepack into flat [q][ch][j=384][dd=16] dwords.
// ---------------------------------------------------------------------------
__global__ void pack_b(const float* __restrict__ w, unsigned* __restrict__ Bp) {
    int ch = blockIdx.x, q = blockIdx.y;
    const float* wr = w + (size_t)q * BS * BS;
    const float* wi = w + (size_t)(4 + q) * BS * BS;
    size_t base = ((size_t)q * 12 + ch) * (384 * 16);
    for (int r = 0; r < 24; r++) {
        int idx = r * 256 + threadIdx.x;       // 0..6143
        int j = idx >> 4, dd = idx & 15;
        int h = j >> 1;
        int dg = ch * 16 + dd;
        float Wr = wr[(size_t)dg * BS + h];
        float Wi = wi[(size_t)dg * BS + h];
        Bp[base + idx] = (j & 1) ? pack2(Wi, Wr) : pack2(Wr, -Wi);
    }
}

// ---------------------------------------------------------------------------
// Kernel 3: FUSED complex MLP, 1024 threads = 16 waves = (m-half, j-group).
// Per wave: acc 3x2 (24 AGPR), 8 A-loads + 3 B-loads + 6 MFMAs per chunk —
// half of R7's per-wave footprint, 2x the resident waves (32/CU wave cap =
// 100% theoretical occupancy at 48KB LDS). Single register set (R8's
// double-buffer crossed the VGPR occupancy cliff; TLP > ILP here).
// ---------------------------------------------------------------------------
__global__ __launch_bounds__(1024) void fused_mlp(const unsigned* __restrict__ Ap,
                                                  const unsigned* __restrict__ Bp1,
                                                  const unsigned* __restrict__ Bp2,
                                                  const float* __restrict__ b1,
                                                  const float* __restrict__ b2,
                                                  unsigned* __restrict__ Yp) {
    __shared__ unsigned hl[192 * 64];   // H panel, XOR-swizzled (hidx)

    const int mblk = blockIdx.x;   // 0..15 (64 m each)
    const int bq   = blockIdx.y;   // 0..255
    const int q    = bq & 3;
    const int tid  = threadIdx.x;
    const int wave = tid >> 6;     // 0..15
    const int mh   = wave >> 3;    // m-half: 0,1 (32 m each)
    const int jw8  = wave & 7;     // j-group: owns j = jw8*48 .. +47
    const int lane = tid & 63;
    const int l15  = lane & 15;
    const int quad = lane >> 4;
    const int jw   = jw8 * 48;

    const unsigned* a_lane = Ap + ((size_t)bq * BS + quad * 4) * NN
                                + mblk * 64 + mh * 32 + l15;
    const size_t bstride = 384 * 16;   // dwords per (q,ch) slab
    const unsigned* b1_lane = Bp1 + (size_t)q * 12 * bstride + (jw + l15) * 16 + quad * 4;
    const unsigned* b2_lane = Bp2 + (size_t)q * 12 * bstride + (jw + l15) * 16 + quad * 4;

    f32x4 acc[3][2];   // acc[tn][tm]
    #pragma unroll
    for (int i = 0; i < 3; i++)
        #pragma unroll
        for (int j = 0; j < 2; j++)
            acc[i][j] = (f32x4)0.f;

    // ---- layer 1: 12 chunks, no barriers ----
    for (int ch = 0; ch < 12; ch++) {
        const unsigned* ap = a_lane + (size_t)(ch * 16) * NN;
        const unsigned* bp = b1_lane + ch * bstride;
        bf16x8 af[2], bfr[3];
        #pragma unroll
        for (int tm = 0; tm < 2; tm++) {
            union { unsigned u[4]; bf16x8 v; } au;
            #pragma unroll
            for (int g = 0; g < 4; g++)
                au.u[g] = ap[(size_t)g * NN + tm * 16];
            af[tm] = au.v;
        }
        #pragma unroll
        for (int tn = 0; tn < 3; tn++) {
            union { uint4 u4; bf16x8 v; } bu;
            bu.u4 = *(const uint4*)(bp + tn * 256);
            bfr[tn] = bu.v;
        }
        #pragma unroll
        for (int tn = 0; tn < 3; tn++)
            #pragma unroll
            for (int tm = 0; tm < 2; tm++)
                acc[tn][tm] = __builtin_amdgcn_mfma_f32_16x16x32_bf16(bfr[tn], af[tm], acc[tn][tm], 0, 0, 0);
    }

    // ---- epilogue 1: bias + ReLU -> bf16 pack -> H-LDS; re-zero acc ----
    #pragma unroll
    for (int tn = 0; tn < 3; tn++) {
        int hg = jw8 * 24 + tn * 8 + quad * 2;   // rows hg, hg+1
        float b0r = b1[q * BS + hg];
        float b0i = b1[768 + q * BS + hg];
        float b1r_ = b1[q * BS + hg + 1];
        float b1i_ = b1[768 + q * BS + hg + 1];
        #pragma unroll
        for (int tm = 0; tm < 2; tm++) {
            int c = mh * 32 + tm * 16 + l15;
            f32x4 a = acc[tn][tm];
            float v0 = fmaxf(a[0] + b0r, 0.f);
            float v1 = fmaxf(a[1] + b0i, 0.f);
            float v2 = fmaxf(a[2] + b1r_, 0.f);
            float v3 = fmaxf(a[3] + b1i_, 0.f);
            hl[hidx(hg, c)]     = pack2(v0, v1);
            hl[hidx(hg + 1, c)] = pack2(v2, v3);
            acc[tn][tm] = (f32x4)0.f;
        }
    }
    __syncthreads();

    // ---- layer 2: 12 chunks over H-LDS, no barriers ----
    for (int ch = 0; ch < 12; ch++) {
        const unsigned* bp = b2_lane + ch * bstride;
        bf16x8 af[2], bfr[3];
        #pragma unroll
        for (int tm = 0; tm < 2; tm++) {
            union { unsigned u[4]; bf16x8 v; } au;
            #pragma unroll
            for (int g = 0; g < 4; g++)
                au.u[g] = hl[hidx(ch * 16 + quad * 4 + g, mh * 32 + tm * 16 + l15)];
            af[tm] = au.v;
        }
        #pragma unroll
        for (int tn = 0; tn < 3; tn++) {
            union { uint4 u4; bf16x8 v; } bu;
            bu.u4 = *(const uint4*)(bp + tn * 256);
            bfr[tn] = bu.v;
        }
        #pragma unroll
        for (int tn = 0; tn < 3; tn++)
            #pragma unroll
            for (int tm = 0; tm < 2; tm++)
                acc[tn][tm] = __builtin_amdgcn_mfma_f32_16x16x32_bf16(bfr[tn], af[tm], acc[tn][tm], 0, 0, 0);
    }

    // ---- epilogue 2: bias + softshrink -> Y plane stores ----
    #pragma unroll
    for (int tn = 0; tn < 3; tn++) {
        int hg = jw8 * 24 + tn * 8 + quad * 2;
        float b0r = b2[q * BS + hg];
        float b0i = b2[768 + q * BS + hg];
        float b1r_ = b2[q * BS + hg + 1];
        float b1i_ = b2[768 + q * BS + hg + 1];
        size_t row0 = ((size_t)bq * BS + hg) * NN + mblk * 64 + mh * 32;
        #pragma unroll
        for (int tm = 0; tm < 2; tm++) {
            int mcol = tm * 16 + l15;
            f32x4 a = acc[tn][tm];
            float v0 = a[0] + b0r, v1 = a[1] + b0i;
            float v2 = a[2] + b1r_, v3 = a[3] + b1i_;
            v0 = (v0 > LAM) ? (v0 - LAM) : ((v0 < -LAM) ? (v0 + LAM) : 0.f);
            v1 = (v1 > LAM) ? (v1 - LAM) : ((v1 < -LAM) ? (v1 + LAM) : 0.f);
            v2 = (v2 > LAM) ? (v2 - LAM) : ((v2 < -LAM) ? (v2 + LAM) : 0.f);
            v3 = (v3 > LAM) ? (v3 - LAM) : ((v3 < -LAM) ? (v3 + LAM) : 0.f);
            Yp[row0 + mcol]      = pack2(v0, v1);
            Yp[row0 + NN + mcol] = pack2(v2, v3);
        }
    }
}

// ---------------------------------------------------------------------------
// Kernel 4: inverse q-IDFT + radix-4 DIT IFFT + residual. Last stage (L=256)
// folded into the epilogue (real parts only).
// ---------------------------------------------------------------------------
__global__ void inv_fft(const float* __restrict__ x,
                        const unsigned* __restrict__ Yp,
                        float* __restrict__ out) {
    __shared__ float2 bufs[4][1024];
    int d = blockIdx.x, b = blockIdx.y, tid = threadIdx.x;

    float Ar[4][4], Ai[4][4];
    size_t qs = (size_t)BS * NN;
    size_t rowb = (((size_t)b * 4) * BS + d) * NN + 4 * tid;
    #pragma unroll
    for (int q = 0; q < 4; q++) {
        uint4 v = *(const uint4*)(Yp + rowb + (size_t)q * qs);
        Ar[q][0] = bflo(v.x); Ai[q][0] = bfhi(v.x);
        Ar[q][1] = bflo(v.y); Ai[q][1] = bfhi(v.y);
        Ar[q][2] = bflo(v.z); Ai[q][2] = bfhi(v.z);
        Ar[q][3] = bflo(v.w); Ai[q][3] = bfhi(v.w);
    }
    #pragma unroll
    for (int m = 0; m < 4; m++) {
        float x0r = Ar[0][m], x0i = Ai[0][m];
        float x1r = Ar[1][m], x1i = Ai[1][m];
        float x2r = Ar[2][m], x2i = Ai[2][m];
        float x3r = Ar[3][m], x3i = Ai[3][m];
        float Y0r = x0r + x1r + x2r + x3r, Y0i = x0i + x1i + x2i + x3i;
        float Y2r = x0r - x1r + x2r - x3r, Y2i = x0i - x1i + x2i - x3i;
        float Y1r = x0r - x1i - x2r + x3i, Y1i = x0i + x1r - x2i - x3r;
        float Y3r = x0r + x1i - x2r - x3i, Y3i = x0i - x1r - x2i + x3r;
        Ar[0][m] = Y0r; Ai[0][m] = Y0i;
        Ar[1][m] = Y1r; Ai[1][m] = Y1i;
        Ar[2][m] = Y2r; Ai[2][m] = Y2i;
        Ar[3][m] = Y3r; Ai[3][m] = Y3i;
    }
    int i0 = swz(4 * tid);
    #pragma unroll
    for (int q = 0; q < 4; q++) {
        float t0r = Ar[q][0] + Ar[q][2], t0i = Ai[q][0] + Ai[q][2];
        float t1r = Ar[q][0] - Ar[q][2], t1i = Ai[q][0] - Ai[q][2];
        float t2r = Ar[q][1] + Ar[q][3], t2i = Ai[q][1] + Ai[q][3];
        float t3r = Ar[q][1] - Ar[q][3], t3i = Ai[q][1] - Ai[q][3];
        float4* p = (float4*)&bufs[q][i0];
        p[0] = make_float4(t0r + t2r, t0i + t2i, t1r - t3i, t1i + t3r);
        p[1] = make_float4(t0r - t2r, t0i - t2i, t1r + t3i, t1i - t3r);
    }
    __syncthreads();

    #pragma unroll
    for (int sL = 0; sL < 3; sL++) {
        const int L = 4 << (2 * sL);
        int j = tid & (L - 1);
        int base = ((tid - j) << 2) + j;
        float s1, c1;
        __sincosf((float)M_PI * 0.5f * (float)j / (float)L, &s1, &c1);
        float c2 = c1 * c1 - s1 * s1, s2 = 2.f * c1 * s1;
        float c3 = c2 * c1 - s2 * s1, s3 = c2 * s1 + s2 * c1;
        #pragma unroll
        for (int q = 0; q < 4; q++) {
            float2 y0 = bufs[q][swz(base)];
            float2 y1 = bufs[q][swz(base + L)];
            float2 y2 = bufs[q][swz(base + 2 * L)];
            float2 y3 = bufs[q][swz(base + 3 * L)];
            float A1r = y1.x * c1 - y1.y * s1, A1i = y1.x * s1 + y1.y * c1;
            float A2r = y2.x * c2 - y2.y * s2, A2i = y2.x * s2 + y2.y * c2;
            float A3r = y3.x * c3 - y3.y * s3, A3i = y3.x * s3 + y3.y * c3;
            float t0r = y0.x + A2r, t0i = y0.y + A2i;
            float t1r = y0.x - A2r, t1i = y0.y - A2i;
            float t2r = A1r + A3r, t2i = A1i + A3i;
            float t3r = A1r - A3r, t3i = A1i - A3i;
            bufs[q][swz(base)]         = make_float2(t0r + t2r, t0i + t2i);
            bufs[q][swz(base + L)]     = make_float2(t1r - t3i, t1i + t3r);
            bufs[q][swz(base + 2 * L)] = make_float2(t0r - t2r, t0i - t2i);
            bufs[q][swz(base + 3 * L)] = make_float2(t1r + t3i, t1i - t3r);
        }
        __syncthreads();
    }

    float s1f, c1f;
    __sincosf((float)M_PI * 0.5f * (float)tid / 256.f, &s1f, &c1f);
    float c2f = c1f * c1f - s1f * s1f, s2f = 2.f * c1f * s1f;
    float c3f = c2f * c1f - s2f * s1f, s3f = c2f * s1f + s2f * c1f;
    const float sc = 1.f / 64.f;
    #pragma unroll
    for (int q = 0; q < 4; q++) {
        float2 y0 = bufs[q][swz(tid)];
        float2 y1 = bufs[q][swz(tid + 256)];
        float2 y2 = bufs[q][swz(tid + 512)];
        float2 y3 = bufs[q][swz(tid + 768)];
        float A1r = y1.x * c1f - y1.y * s1f, A1i = y1.x * s1f + y1.y * c1f;
        float A2r = y2.x * c2f - y2.y * s2f;
        float A3r = y3.x * c3f - y3.y * s3f, A3i = y3.x * s3f + y3.y * c3f;
        float t0r = y0.x + A2r;
        float t1r = y0.x - A2r;
        float t2r = A1r + A3r;
        float t3i = A1i - A3i;
        size_t row = (((size_t)b * 4 + q) * BS + d) * NN;
        const float* xp = x + row;
        out[row + tid]       = (t0r + t2r) * sc + xp[tid];
        out[row + tid + 256] = (t1r - t3i) * sc + xp[tid + 256];
        out[row + tid + 512] = (t0r - t2r) * sc + xp[tid + 512];
        out[row + tid + 768] = (t1r + t3i) * sc + xp[tid + 768];
    }
}

// ---------------------------------------------------------------------------
extern "C" void kernel_launch(void* const* d_in, const int* in_sizes, int n_in,
                              void* d_out, int out_size, void* d_ws, size_t ws_size,
                              hipStream_t stream) {
    const float* x     = (const float*)d_in[0];
    const float* w1    = (const float*)d_in[1];
    const float* w2    = (const float*)d_in[2];
    const float* b1    = (const float*)d_in[3];
    const float* b2    = (const float*)d_in[4];
    const float* gamma = (const float*)d_in[5];
    const float* beta  = (const float*)d_in[6];

    unsigned* Xp = (unsigned*)d_ws;
    float* mu    = (float*)d_ws + (size_t)BB * CC * NN;
    float* rstd  = mu + (size_t)BB * NN;
    unsigned* Bp1 = (unsigned*)(rstd + (size_t)BB * NN);
    unsigned* Bp2 = Bp1 + (size_t)4 * 12 * 384 * 16;
    unsigned* Yp = Xp;   // layer-2 output overwrites X region (disjoint m-cols per block)

    pack_b<<<dim3(12, 4), 256, 0, stream>>>(w1, Bp1);
    pack_b<<<dim3(12, 4), 256, 0, stream>>>(w2, Bp2);
    ln_stats<<<dim3(NN / 256, BB), 512, 0, stream>>>(x, mu, rstd);
    fwd_fft<<<dim3(BS, BB), 256, 0, stream>>>(x, mu, rstd, gamma, beta, Xp);
    fused_mlp<<<dim3(16, 256), 1024, 0, stream>>>(Xp, Bp1, Bp2, b1, b2, Yp);
    inv_fft<<<dim3(BS, BB), 256, 0, stream>>>(x, Yp, (float*)d_out);
}

// Round 10
// 699.565 us; speedup vs baseline: 1.2725x; 1.2725x over previous
//
#include <hip/hip_runtime.h>
#include <math.h>

#define BB 64
#define CC 768
#define NN 1024
#define BS 192
#define EPS 1e-5f
#define LAM 0.01f

typedef float  f32x4  __attribute__((ext_vector_type(4)));
typedef short  bf16x8 __attribute__((ext_vector_type(8)));

__device__ inline unsigned f2bf(float x) {
    unsigned u = __float_as_uint(x);
    u += 0x7fff + ((u >> 16) & 1);   // RNE
    return u >> 16;
}
__device__ inline unsigned pack2(float r, float i) { return f2bf(r) | (f2bf(i) << 16); }
__device__ inline float bflo(unsigned v) { return __uint_as_float(v << 16); }
__device__ inline float bfhi(unsigned v) { return __uint_as_float(v & 0xffff0000u); }

// LDS bank swizzle on float2 index (FFT kernels only): XOR bits 4-5 into 2-3.
__device__ inline int swz(int i) { return i ^ (((i >> 4) & 3) << 2); }

// ---------------------------------------------------------------------------
// Kernel 1: LayerNorm statistics per (b, n). float4-vectorized along n.
// ---------------------------------------------------------------------------
__global__ __launch_bounds__(512) void ln_stats(const float* __restrict__ x,
                                                float* __restrict__ mu,
                                                float* __restrict__ rstd) {
    int tn = threadIdx.x & 63, tc = threadIdx.x >> 6;   // tc: 0..7
    int n = blockIdx.x * 256 + tn * 4, b = blockIdx.y;
    const float* xp = x + (size_t)b * CC * NN + n;
    f32x4 s = (f32x4)0.f, ss = (f32x4)0.f;
    #pragma unroll 4
    for (int c = tc; c < CC; c += 8) {
        f32x4 v = *(const f32x4*)(xp + (size_t)c * NN);
        s += v; ss += v * v;
    }
    __shared__ f32x4 sm[8][64], sq[8][64];
    sm[tc][tn] = s; sq[tc][tn] = ss;
    __syncthreads();
    if (tc == 0) {
        f32x4 S  = sm[0][tn], SS = sq[0][tn];
        #pragma unroll
        for (int i = 1; i < 8; i++) { S += sm[i][tn]; SS += sq[i][tn]; }
        f32x4 m = S * (1.f / 768.f);
        f32x4 r;
        #pragma unroll
        for (int i = 0; i < 4; i++) {
            float var = SS[i] * (1.f / 768.f) - m[i] * m[i];
            r[i] = rsqrtf(var + EPS);
        }
        *(f32x4*)(mu + (size_t)b * NN + n)   = m;
        *(f32x4*)(rstd + (size_t)b * NN + n) = r;
    }
}

// ---------------------------------------------------------------------------
// Kernel 2: LN-apply + 1024-pt radix-4 DIF FFT (n) + 4-pt DFT (q) + 1/64.
// First stage (L=256) folded into the LN-load.
// ---------------------------------------------------------------------------
__global__ void fwd_fft(const float* __restrict__ x,
                        const float* __restrict__ mu_, const float* __restrict__ rs_,
                        const float* __restrict__ gamma, const float* __restrict__ beta,
                        unsigned* __restrict__ Xp) {
    __shared__ float2 bufs[4][1024];
    int d = blockIdx.x, b = blockIdx.y, tid = threadIdx.x;

    float s1f, c1f;
    __sincosf(-(float)M_PI * 0.5f * (float)tid / 256.f, &s1f, &c1f);
    float c2f = c1f * c1f - s1f * s1f, s2f = 2.f * c1f * s1f;
    float c3f = c2f * c1f - s2f * s1f, s3f = c2f * s1f + s2f * c1f;

    const float* mp = mu_ + b * NN;
    const float* rp = rs_ + b * NN;
    #pragma unroll
    for (int q = 0; q < 4; q++) {
        int c = q * BS + d;
        float g = gamma[c], be = beta[c];
        const float* xp = x + ((size_t)b * CC + c) * NN;
        float v0 = (xp[tid]       - mp[tid])       * rp[tid]       * g + be;
        float v1 = (xp[tid + 256] - mp[tid + 256]) * rp[tid + 256] * g + be;
        float v2 = (xp[tid + 512] - mp[tid + 512]) * rp[tid + 512] * g + be;
        float v3 = (xp[tid + 768] - mp[tid + 768]) * rp[tid + 768] * g + be;
        float t0 = v0 + v2, t1 = v0 - v2, t2 = v1 + v3, t3 = v1 - v3;
        bufs[q][swz(tid)]       = make_float2(t0 + t2, 0.f);
        bufs[q][swz(tid + 256)] = make_float2(t1 * c1f + t3 * s1f, t1 * s1f - t3 * c1f);
        bufs[q][swz(tid + 512)] = make_float2((t0 - t2) * c2f, (t0 - t2) * s2f);
        bufs[q][swz(tid + 768)] = make_float2(t1 * c3f - t3 * s3f, t1 * s3f + t3 * c3f);
    }
    __syncthreads();

    #pragma unroll
    for (int sL = 0; sL < 3; sL++) {
        const int L = 64 >> (2 * sL);
        int j = tid & (L - 1);
        int base = ((tid - j) << 2) + j;
        float s1, c1;
        __sincosf(-(float)M_PI * 0.5f * (float)j / (float)L, &s1, &c1);
        float c2 = c1 * c1 - s1 * s1, s2 = 2.f * c1 * s1;
        float c3 = c2 * c1 - s2 * s1, s3 = c2 * s1 + s2 * c1;
        #pragma unroll
        for (int q = 0; q < 4; q++) {
            float2 a  = bufs[q][swz(base)];
            float2 bb = bufs[q][swz(base + L)];
            float2 cc = bufs[q][swz(base + 2 * L)];
            float2 dd = bufs[q][swz(base + 3 * L)];
            float t0r = a.x + cc.x, t0i = a.y + cc.y;
            float t1r = a.x - cc.x, t1i = a.y - cc.y;
            float t2r = bb.x + dd.x, t2i = bb.y + dd.y;
            float t3r = bb.x - dd.x, t3i = bb.y - dd.y;
            float X0r = t0r + t2r, X0i = t0i + t2i;
            float X2r = t0r - t2r, X2i = t0i - t2i;
            float X1r = t1r + t3i, X1i = t1i - t3r;
            float X3r = t1r - t3i, X3i = t1i + t3r;
            bufs[q][swz(base)]         = make_float2(X0r, X0i);
            bufs[q][swz(base + L)]     = make_float2(X1r * c1 - X1i * s1, X1r * s1 + X1i * c1);
            bufs[q][swz(base + 2 * L)] = make_float2(X2r * c2 - X2i * s2, X2r * s2 + X2i * c2);
            bufs[q][swz(base + 3 * L)] = make_float2(X3r * c3 - X3i * s3, X3r * s3 + X3i * c3);
        }
        __syncthreads();
    }

    float Xr[4][4], Xi[4][4];
    int i0 = swz(4 * tid);
    #pragma unroll
    for (int q = 0; q < 4; q++) {
        const float4* p = (const float4*)&bufs[q][i0];
        float4 u0 = p[0], u1 = p[1];
        float t0r = u0.x + u1.x, t0i = u0.y + u1.y;
        float t1r = u0.x - u1.x, t1i = u0.y - u1.y;
        float t2r = u0.z + u1.z, t2i = u0.w + u1.w;
        float t3r = u0.z - u1.z, t3i = u0.w - u1.w;
        Xr[q][0] = t0r + t2r; Xi[q][0] = t0i + t2i;
        Xr[q][1] = t1r + t3i; Xi[q][1] = t1i - t3r;
        Xr[q][2] = t0r - t2r; Xi[q][2] = t0i - t2i;
        Xr[q][3] = t1r - t3i; Xi[q][3] = t1i + t3r;
    }
    const float sc = 1.f / 64.f;
    unsigned o0[4], o1[4], o2[4], o3[4];
    #pragma unroll
    for (int m = 0; m < 4; m++) {
        float x0r = Xr[0][m], x0i = Xi[0][m];
        float x1r = Xr[1][m], x1i = Xi[1][m];
        float x2r = Xr[2][m], x2i = Xi[2][m];
        float x3r = Xr[3][m], x3i = Xi[3][m];
        float X0r = x0r + x1r + x2r + x3r, X0i = x0i + x1i + x2i + x3i;
        float X2r = x0r - x1r + x2r - x3r, X2i = x0i - x1i + x2i - x3i;
        float X1r = x0r + x1i - x2r - x3i, X1i = x0i - x1r - x2i + x3r;
        float X3r = x0r - x1i - x2r + x3i, X3i = x0i + x1r - x2i - x3r;
        o0[m] = pack2(X0r * sc, X0i * sc);
        o1[m] = pack2(X1r * sc, X1i * sc);
        o2[m] = pack2(X2r * sc, X2i * sc);
        o3[m] = pack2(X3r * sc, X3i * sc);
    }
    size_t qs = (size_t)BS * NN;
    size_t base = (((size_t)b * 4) * BS + d) * NN + 4 * tid;
    *(uint4*)(Xp + base)          = make_uint4(o0[0], o0[1], o0[2], o0[3]);
    *(uint4*)(Xp + base + qs)     = make_uint4(o1[0], o1[1], o1[2], o1[3]);
    *(uint4*)(Xp + base + 2 * qs) = make_uint4(o2[0], o2[1], o2[2], o2[3]);
    *(uint4*)(Xp + base + 3 * qs) = make_uint4(o3[0], o3[1], o3[2], o3[3]);
}

// ---------------------------------------------------------------------------
// Kernel 2b: one-time B prepack into flat [q][ch][j=384][dd=16] dwords.
// ---------------------------------------------------------------------------
__global__ void pack_b(const float* __restrict__ w, unsigned* __restrict__ Bp) {
    int ch = blockIdx.x, q = blockIdx.y;
    const float* wr = w + (size_t)q * BS * BS;
    const float* wi = w + (size_t)(4 + q) * BS * BS;
    size_t base = ((size_t)q * 12 + ch) * (384 * 16);
    for (int r = 0; r < 24; r++) {
        int idx = r * 256 + threadIdx.x;       // 0..6143
        int j = idx >> 4, dd = idx & 15;
        int h = j >> 1;
        int dg = ch * 16 + dd;
        float Wr = wr[(size_t)dg * BS + h];
        float Wi = wi[(size_t)dg * BS + h];
        Bp[base + idx] = (j & 1) ? pack2(Wi, Wr) : pack2(Wr, -Wi);
    }
}

// ---------------------------------------------------------------------------
// Kernel 3: FUSED complex MLP, 512 threads = 8 j-waves (R7 skeleton).
// Single 48 KB LDS panel in k-interleaved layout
//   idx(r,c) = (r>>2)*256 + c*4 + (r&3)
// used TWICE: A panel (staged once, shared by all 8 j-waves -> deletes the
// 8x-redundant per-chunk global A-loads that bounded R7), then overwritten
// by H between layers. Every fragment load is ONE ds_read_b128.
// Bank audit: staging write 2 lanes/bank; frag read contiguous 256B/quad;
// H-write uint2 pairs at b64 floor. 3 barriers total.
// ---------------------------------------------------------------------------
__global__ __launch_bounds__(512) void fused_mlp(const unsigned* __restrict__ Ap,
                                                 const unsigned* __restrict__ Bp1,
                                                 const unsigned* __restrict__ Bp2,
                                                 const float* __restrict__ b1,
                                                 const float* __restrict__ b2,
                                                 unsigned* __restrict__ Yp) {
    __shared__ __align__(16) unsigned tl[12288];   // 48 KB shared panel

    const int mblk = blockIdx.x;   // 0..15 (64 m each)
    const int bq   = blockIdx.y;   // 0..255
    const int q    = bq & 3;
    const int tid  = threadIdx.x;
    const int wave = tid >> 6;     // 0..7: j-group, owns j = wave*48..+47
    const int lane = tid & 63;
    const int l15  = lane & 15;
    const int quad = lane >> 4;
    const int jw   = wave * 48;

    const size_t bstride = 384 * 16;   // dwords per (q,ch) slab
    const unsigned* b1_lane = Bp1 + (size_t)q * 12 * bstride + (jw + l15) * 16 + quad * 4;
    const unsigned* b2_lane = Bp2 + (size_t)q * 12 * bstride + (jw + l15) * 16 + quad * 4;

    // ---- stage A panel (192 rows x 64 cols) into k-interleaved LDS ----
    {
        const unsigned* abase = Ap + ((size_t)bq * BS) * NN + (size_t)mblk * 64;
        unsigned st[24];
        #pragma unroll
        for (int i = 0; i < 6; i++) {
            int r = (i * 8 + wave) * 4 + quad;
            const unsigned* gp = abase + (size_t)r * NN + l15;
            #pragma unroll
            for (int k = 0; k < 4; k++) st[i * 4 + k] = gp[16 * k];
        }
        #pragma unroll
        for (int i = 0; i < 6; i++) {
            int s = i * 8 + wave;
            unsigned* lp = &tl[s * 256 + quad];
            #pragma unroll
            for (int k = 0; k < 4; k++) lp[(l15 + 16 * k) * 4] = st[i * 4 + k];
        }
    }

    f32x4 acc[3][4];   // acc[tn][tm]
    #pragma unroll
    for (int i = 0; i < 3; i++)
        #pragma unroll
        for (int j = 0; j < 4; j++)
            acc[i][j] = (f32x4)0.f;

    __syncthreads();

    // ---- layer 1: 12 chunks; A-frags = 1 ds_read_b128 each ----
    for (int ch = 0; ch < 12; ch++) {
        const unsigned* tp = &tl[(ch * 4 + quad) * 256];
        const unsigned* bp = b1_lane + ch * bstride;
        bf16x8 af[4], bfr[3];
        #pragma unroll
        for (int tm = 0; tm < 4; tm++)
            af[tm] = *(const bf16x8*)(tp + (tm * 16 + l15) * 4);
        #pragma unroll
        for (int tn = 0; tn < 3; tn++) {
            union { uint4 u4; bf16x8 v; } bu;
            bu.u4 = *(const uint4*)(bp + tn * 256);
            bfr[tn] = bu.v;
        }
        #pragma unroll
        for (int tn = 0; tn < 3; tn++)
            #pragma unroll
            for (int tm = 0; tm < 4; tm++)
                acc[tn][tm] = __builtin_amdgcn_mfma_f32_16x16x32_bf16(bfr[tn], af[tm], acc[tn][tm], 0, 0, 0);
    }

    __syncthreads();   // all waves done reading A before H overwrites

    // ---- epilogue 1: bias + ReLU -> bf16 pack -> H into same LDS ----
    #pragma unroll
    for (int tn = 0; tn < 3; tn++) {
        int hg = jw >> 1;  // wave*24
        hg += tn * 8 + quad * 2;                  // rows hg, hg+1
        float b0r = b1[q * BS + hg];
        float b0i = b1[768 + q * BS + hg];
        float b1r_ = b1[q * BS + hg + 1];
        float b1i_ = b1[768 + q * BS + hg + 1];
        #pragma unroll
        for (int tm = 0; tm < 4; tm++) {
            int c = tm * 16 + l15;
            f32x4 a = acc[tn][tm];
            float v0 = fmaxf(a[0] + b0r, 0.f);
            float v1 = fmaxf(a[1] + b0i, 0.f);
            float v2 = fmaxf(a[2] + b1r_, 0.f);
            float v3 = fmaxf(a[3] + b1i_, 0.f);
            unsigned* hp = &tl[(hg >> 2) * 256 + c * 4 + (hg & 3)];
            *(uint2*)hp = make_uint2(pack2(v0, v1), pack2(v2, v3));
            acc[tn][tm] = (f32x4)0.f;
        }
    }
    __syncthreads();

    // ---- layer 2: 12 chunks over H-LDS, same access shape ----
    for (int ch = 0; ch < 12; ch++) {
        const unsigned* tp = &tl[(ch * 4 + quad) * 256];
        const unsigned* bp = b2_lane + ch * bstride;
        bf16x8 af[4], bfr[3];
        #pragma unroll
        for (int tm = 0; tm < 4; tm++)
            af[tm] = *(const bf16x8*)(tp + (tm * 16 + l15) * 4);
        #pragma unroll
        for (int tn = 0; tn < 3; tn++) {
            union { uint4 u4; bf16x8 v; } bu;
            bu.u4 = *(const uint4*)(bp + tn * 256);
            bfr[tn] = bu.v;
        }
        #pragma unroll
        for (int tn = 0; tn < 3; tn++)
            #pragma unroll
            for (int tm = 0; tm < 4; tm++)
                acc[tn][tm] = __builtin_amdgcn_mfma_f32_16x16x32_bf16(bfr[tn], af[tm], acc[tn][tm], 0, 0, 0);
    }

    // ---- epilogue 2: bias + softshrink -> Y plane stores ----
    #pragma unroll
    for (int tn = 0; tn < 3; tn++) {
        int hg = (jw >> 1) + tn * 8 + quad * 2;
        float b0r = b2[q * BS + hg];
        float b0i = b2[768 + q * BS + hg];
        float b1r_ = b2[q * BS + hg + 1];
        float b1i_ = b2[768 + q * BS + hg + 1];
        size_t row0 = ((size_t)bq * BS + hg) * NN + (size_t)mblk * 64;
        #pragma unroll
        for (int tm = 0; tm < 4; tm++) {
            int mcol = tm * 16 + l15;
            f32x4 a = acc[tn][tm];
            float v0 = a[0] + b0r, v1 = a[1] + b0i;
            float v2 = a[2] + b1r_, v3 = a[3] + b1i_;
            v0 = (v0 > LAM) ? (v0 - LAM) : ((v0 < -LAM) ? (v0 + LAM) : 0.f);
            v1 = (v1 > LAM) ? (v1 - LAM) : ((v1 < -LAM) ? (v1 + LAM) : 0.f);
            v2 = (v2 > LAM) ? (v2 - LAM) : ((v2 < -LAM) ? (v2 + LAM) : 0.f);
            v3 = (v3 > LAM) ? (v3 - LAM) : ((v3 < -LAM) ? (v3 + LAM) : 0.f);
            Yp[row0 + mcol]      = pack2(v0, v1);
            Yp[row0 + NN + mcol] = pack2(v2, v3);
        }
    }
}

// ---------------------------------------------------------------------------
// Kernel 4: inverse q-IDFT + radix-4 DIT IFFT + residual. Last stage (L=256)
// folded into the epilogue (real parts only).
// ---------------------------------------------------------------------------
__global__ void inv_fft(const float* __restrict__ x,
                        const unsigned* __restrict__ Yp,
                        float* __restrict__ out) {
    __shared__ float2 bufs[4][1024];
    int d = blockIdx.x, b = blockIdx.y, tid = threadIdx.x;

    float Ar[4][4], Ai[4][4];
    size_t qs = (size_t)BS * NN;
    size_t rowb = (((size_t)b * 4) * BS + d) * NN + 4 * tid;
    #pragma unroll
    for (int q = 0; q < 4; q++) {
        uint4 v = *(const uint4*)(Yp + rowb + (size_t)q * qs);
        Ar[q][0] = bflo(v.x); Ai[q][0] = bfhi(v.x);
        Ar[q][1] = bflo(v.y); Ai[q][1] = bfhi(v.y);
        Ar[q][2] = bflo(v.z); Ai[q][2] = bfhi(v.z);
        Ar[q][3] = bflo(v.w); Ai[q][3] = bfhi(v.w);
    }
    #pragma unroll
    for (int m = 0; m < 4; m++) {
        float x0r = Ar[0][m], x0i = Ai[0][m];
        float x1r = Ar[1][m], x1i = Ai[1][m];
        float x2r = Ar[2][m], x2i = Ai[2][m];
        float x3r = Ar[3][m], x3i = Ai[3][m];
        float Y0r = x0r + x1r + x2r + x3r, Y0i = x0i + x1i + x2i + x3i;
        float Y2r = x0r - x1r + x2r - x3r, Y2i = x0i - x1i + x2i - x3i;
        float Y1r = x0r - x1i - x2r + x3i, Y1i = x0i + x1r - x2i - x3r;
        float Y3r = x0r + x1i - x2r - x3i, Y3i = x0i - x1r - x2i + x3r;
        Ar[0][m] = Y0r; Ai[0][m] = Y0i;
        Ar[1][m] = Y1r; Ai[1][m] = Y1i;
        Ar[2][m] = Y2r; Ai[2][m] = Y2i;
        Ar[3][m] = Y3r; Ai[3][m] = Y3i;
    }
    int i0 = swz(4 * tid);
    #pragma unroll
    for (int q = 0; q < 4; q++) {
        float t0r = Ar[q][0] + Ar[q][2], t0i = Ai[q][0] + Ai[q][2];
        float t1r = Ar[q][0] - Ar[q][2], t1i = Ai[q][0] - Ai[q][2];
        float t2r = Ar[q][1] + Ar[q][3], t2i = Ai[q][1] + Ai[q][3];
        float t3r = Ar[q][1] - Ar[q][3], t3i = Ai[q][1] - Ai[q][3];
        float4* p = (float4*)&bufs[q][i0];
        p[0] = make_float4(t0r + t2r, t0i + t2i, t1r - t3i, t1i + t3r);
        p[1] = make_float4(t0r - t2r, t0i - t2i, t1r + t3i, t1i - t3r);
    }
    __syncthreads();

    #pragma unroll
    for (int sL = 0; sL < 3; sL++) {
        const int L = 4 << (2 * sL);
        int j = tid & (L - 1);
        int base = ((tid - j) << 2) + j;
        float s1, c1;
        __sincosf((float)M_PI * 0.5f * (float)j / (float)L, &s1, &c1);
        float c2 = c1 * c1 - s1 * s1, s2 = 2.f * c1 * s1;
        float c3 = c2 * c1 - s2 * s1, s3 = c2 * s1 + s2 * c1;
        #pragma unroll
        for (int q = 0; q < 4; q++) {
            float2 y0 = bufs[q][swz(base)];
            float2 y1 = bufs[q][swz(base + L)];
            float2 y2 = bufs[q][swz(base + 2 * L)];
            float2 y3 = bufs[q][swz(base + 3 * L)];
            float A1r = y1.x * c1 - y1.y * s1, A1i = y1.x * s1 + y1.y * c1;
            float A2r = y2.x * c2 - y2.y * s2, A2i = y2.x * s2 + y2.y * c2;
            float A3r = y3.x * c3 - y3.y * s3, A3i = y3.x * s3 + y3.y * c3;
            float t0r = y0.x + A2r, t0i = y0.y + A2i;
            float t1r = y0.x - A2r, t1i = y0.y - A2i;
            float t2r = A1r + A3r, t2i = A1i + A3i;
            float t3r = A1r - A3r, t3i = A1i - A3i;
            bufs[q][swz(base)]         = make_float2(t0r + t2r, t0i + t2i);
            bufs[q][swz(base + L)]     = make_float2(t1r - t3i, t1i + t3r);
            bufs[q][swz(base + 2 * L)] = make_float2(t0r - t2r, t0i - t2i);
            bufs[q][swz(base + 3 * L)] = make_float2(t1r + t3i, t1i - t3r);
        }
        __syncthreads();
    }

    float s1f, c1f;
    __sincosf((float)M_PI * 0.5f * (float)tid / 256.f, &s1f, &c1f);
    float c2f = c1f * c1f - s1f * s1f, s2f = 2.f * c1f * s1f;
    float c3f = c2f * c1f - s2f * s1f, s3f = c2f * s1f + s2f * c1f;
    const float sc = 1.f / 64.f;
    #pragma unroll
    for (int q = 0; q < 4; q++) {
        float2 y0 = bufs[q][swz(tid)];
        float2 y1 = bufs[q][swz(tid + 256)];
        float2 y2 = bufs[q][swz(tid + 512)];
        float2 y3 = bufs[q][swz(tid + 768)];
        float A1r = y1.x * c1f - y1.y * s1f, A1i = y1.x * s1f + y1.y * c1f;
        float A2r = y2.x * c2f - y2.y * s2f;
        float A3r = y3.x * c3f - y3.y * s3f, A3i = y3.x * s3f + y3.y * c3f;
        float t0r = y0.x + A2r;
        float t1r = y0.x - A2r;
        float t2r = A1r + A3r;
        float t3i = A1i - A3i;
        size_t row = (((size_t)b * 4 + q) * BS + d) * NN;
        const float* xp = x + row;
        out[row + tid]       = (t0r + t2r) * sc + xp[tid];
        out[row + tid + 256] = (t1r - t3i) * sc + xp[tid + 256];
        out[row + tid + 512] = (t0r - t2r) * sc + xp[tid + 512];
        out[row + tid + 768] = (t1r + t3i) * sc + xp[tid + 768];
    }
}

// ---------------------------------------------------------------------------
extern "C" void kernel_launch(void* const* d_in, const int* in_sizes, int n_in,
                              void* d_out, int out_size, void* d_ws, size_t ws_size,
                              hipStream_t stream) {
    const float* x     = (const float*)d_in[0];
    const float* w1    = (const float*)d_in[1];
    const float* w2    = (const float*)d_in[2];
    const float* b1    = (const float*)d_in[3];
    const float* b2    = (const float*)d_in[4];
    const float* gamma = (const float*)d_in[5];
    const float* beta  = (const float*)d_in[6];

    unsigned* Xp = (unsigned*)d_ws;
    float* mu    = (float*)d_ws + (size_t)BB * CC * NN;
    float* rstd  = mu + (size_t)BB * NN;
    unsigned* Bp1 = (unsigned*)(rstd + (size_t)BB * NN);
    unsigned* Bp2 = Bp1 + (size_t)4 * 12 * 384 * 16;
    unsigned* Yp = Xp;   // layer-2 output overwrites X region (disjoint m-cols per block)

    pack_b<<<dim3(12, 4), 256, 0, stream>>>(w1, Bp1);
    pack_b<<<dim3(12, 4), 256, 0, stream>>>(w2, Bp2);
    ln_stats<<<dim3(NN / 256, BB), 512, 0, stream>>>(x, mu, rstd);
    fwd_fft<<<dim3(BS, BB), 256, 0, stream>>>(x, mu, rstd, gamma, beta, Xp);
    fused_mlp<<<dim3(16, 256), 512, 0, stream>>>(Xp, Bp1, Bp2, b1, b2, Yp);
    inv_fft<<<dim3(BS, BB), 256, 0, stream>>>(x, Yp, (float*)d_out);
}